// Round 15
// baseline (73.184 us; speedup 1.0000x reference)
//
#include <hip/hip_runtime.h>
#include <hip/hip_bf16.h>

typedef unsigned short u16;
typedef __attribute__((ext_vector_type(8))) __bf16 bf16x8;
typedef __attribute__((ext_vector_type(8))) unsigned short u16x8;
typedef __attribute__((ext_vector_type(4))) float f32x4;
typedef __attribute__((ext_vector_type(4))) unsigned short u16x4;

#define SEQ 4096
#define DIM 1024
#define NH 16
#define HD 64
#define WIN 256
#define NT32 (SEQ / 32)
#define NKT 32   // K-tiles of 32 in K=1024 (projection GEMM)
#define BQ 128   // q-rows per attention block

__device__ inline u16 f2bf(float f) {
  __hip_bfloat16 h = __float2bfloat16(f);
  return __builtin_bit_cast(u16, h);
}

__device__ inline void gload_lds16(const void* g, void* l) {
  auto gp = reinterpret_cast<__attribute__((address_space(1))) unsigned int*>(
      reinterpret_cast<unsigned long long>(g));
  auto lp = reinterpret_cast<__attribute__((address_space(3))) unsigned int*>(
      reinterpret_cast<unsigned long long>(l));
  __builtin_amdgcn_global_load_lds(gp, lp, 16, 0, 0);
}

// Fused cast (hidden + 3 weights -> bf16) + aux pack (bias cat + fm mask table).
__global__ __launch_bounds__(256) void cast_all(const float* __restrict__ hsrc,
                                                const float* __restrict__ w0, const float* __restrict__ w1,
                                                const float* __restrict__ w2,
                                                const float* __restrict__ b0, const float* __restrict__ b1,
                                                const float* __restrict__ b2, const float* __restrict__ amask,
                                                u16* __restrict__ Hb, u16* __restrict__ Wcat,
                                                float* __restrict__ aux) {
  const int bid = blockIdx.x;
  if (bid < 7168) {
    int i = (bid * 256 + threadIdx.x) * 4;
    const float* src;
    u16* dst;
    if (i < (1 << 22)) { src = hsrc + i; dst = Hb + i; }
    else {
      int j = i - (1 << 22);
      const int seg = j >> 20, loc = j & ((1 << 20) - 1);
      src = ((seg == 0) ? w0 : (seg == 1) ? w1 : w2) + loc;
      dst = Wcat + j;
    }
    const float4 v = *reinterpret_cast<const float4*>(src);
    u16x4 r;
    r.x = f2bf(v.x); r.y = f2bf(v.y); r.z = f2bf(v.z); r.w = f2bf(v.w);
    *reinterpret_cast<u16x4*>(dst) = r;
  } else {
    int i = (bid - 7168) * 256 + threadIdx.x;   // 0..7167
    if (i < 3072) {
      const int seg = i >> 10, loc = i & 1023;
      aux[i] = (seg == 0) ? b0[loc] : (seg == 1) ? b1[loc] : b2[loc];
    } else {
      const int j = i - 3072;
      aux[i] = (amask[j] != 0.f) ? -14426.95f : 0.f;   // -10000/ln2
    }
  }
}

// ---- GEMM: 128x128 tile, BK=32, 4 waves (2x2), NBUF=4, prefetch distance 3,
// counted vmcnt (4 loads/thread/tile: steady wait = 8 = 2 tiles in flight).
// Both-sides XOR-swizzled LDS (linear dest, pre-swizzled source, swizzled read):
// 16B unit u = sr*8 + half*4 + sp holds global (row = sr*2+half, slot = sp^(sr&3));
// read elem = (row>>1)*64 + (row&1)*32 + (lgrp^((row>>1)&3))*8 -> 2 lanes/bank (free).
__device__ __forceinline__ void stage_tile(const u16* __restrict__ A, const u16* __restrict__ B,
                                           int bm, int bn, u16* sa, u16* sb, int kt, int tid) {
  const int k0 = kt * 32;
#pragma unroll
  for (int l = 0; l < 2; ++l) {              // 512 units of 16B per matrix (full 8KB tile)
    const int u = l * 256 + tid;
    const int sr = u >> 3, half = (u >> 2) & 1, sp = u & 3;
    const int row = sr * 2 + half;
    const int slot = sp ^ (sr & 3);
    gload_lds16(A + (size_t)(bm + row) * DIM + k0 + slot * 8, sa + u * 8);
    gload_lds16(B + (size_t)(bn + row) * DIM + k0 + slot * 8, sb + u * 8);
  }
}

// Fused QKV projection.
// Cols 0-1023    -> Qh [NH][S][64]  (x 0.125/ln2, exp2 trick)
// Cols 1024-2047 -> Kh [NH][S][64]
// Cols 2048-3071 -> Vtile [NH][S/32][64][32], sigma-permuted keys (zero-shuffle PV).
__global__ __launch_bounds__(256, 2) void gemm_qkv(const u16* __restrict__ A, const u16* __restrict__ B,
                                                   const float* __restrict__ bias,
                                                   u16* __restrict__ Qh, u16* __restrict__ Kh,
                                                   u16* __restrict__ Vtile) {
  __shared__ __align__(16) u16 SA[4][128 * 32];
  __shared__ __align__(16) u16 SB[4][128 * 32];
  const int nwgx = gridDim.x;                        // 24
  const int orig = blockIdx.y * nwgx + blockIdx.x;   // 0..767
  const int cpx = (nwgx * gridDim.y) >> 3;           // 96
  const int wgid = (orig & 7) * cpx + (orig >> 3);   // bijective (768%8==0)
  const int bm = (wgid / nwgx) * 128, bn = (wgid % nwgx) * 128;
  const int tid = threadIdx.x;
  const int lane = tid & 63, wid = tid >> 6;
  const int lrow = lane & 15, lgrp = lane >> 4;
  const int wr = (wid >> 1) * 64, wc = (wid & 1) * 64;

  f32x4 acc[4][4];
  const f32x4 zero = {0.f, 0.f, 0.f, 0.f};
#pragma unroll
  for (int m = 0; m < 4; ++m)
#pragma unroll
    for (int n = 0; n < 4; ++n) acc[m][n] = zero;

  stage_tile(A, B, bm, bn, SA[0], SB[0], 0, tid);
  stage_tile(A, B, bm, bn, SA[1], SB[1], 1, tid);
  stage_tile(A, B, bm, bn, SA[2], SB[2], 2, tid);
  asm volatile("s_waitcnt vmcnt(8)" ::: "memory");   // tile0 landed (1,2 in flight)
  asm volatile("s_barrier" ::: "memory");

  for (int t = 0; t < NKT; ++t) {
    const int s = t & 3;
    if (t + 3 < NKT) stage_tile(A, B, bm, bn, SA[(t + 3) & 3], SB[(t + 3) & 3], t + 3, tid);
    bf16x8 af[4], bfr[4];
#pragma unroll
    for (int m = 0; m < 4; ++m) {
      const int row = wr + m * 16 + lrow;
      af[m] = *reinterpret_cast<const bf16x8*>(
          &SA[s][(row >> 1) * 64 + (row & 1) * 32 + ((lgrp ^ ((row >> 1) & 3)) * 8)]);
    }
#pragma unroll
    for (int n = 0; n < 4; ++n) {
      const int row = wc + n * 16 + lrow;
      bfr[n] = *reinterpret_cast<const bf16x8*>(
          &SB[s][(row >> 1) * 64 + (row & 1) * 32 + ((lgrp ^ ((row >> 1) & 3)) * 8)]);
    }
    __builtin_amdgcn_s_setprio(1);
#pragma unroll
    for (int m = 0; m < 4; ++m)
#pragma unroll
      for (int n = 0; n < 4; ++n)
        acc[m][n] = __builtin_amdgcn_mfma_f32_16x16x32_bf16(af[m], bfr[n], acc[m][n], 0, 0, 0);
    __builtin_amdgcn_s_setprio(0);
    if (t + 3 < NKT)      { asm volatile("s_waitcnt vmcnt(8)" ::: "memory"); }
    else if (t + 2 < NKT) { asm volatile("s_waitcnt vmcnt(4)" ::: "memory"); }
    else if (t + 1 < NKT) { asm volatile("s_waitcnt vmcnt(0)" ::: "memory"); }
    asm volatile("s_barrier" ::: "memory");
  }

#pragma unroll
  for (int m = 0; m < 4; ++m)
#pragma unroll
    for (int n = 0; n < 4; ++n) {
      const int row0 = bm + wr + m * 16 + lgrp * 4;
      const int colg = bn + wc + n * 16 + lrow;
      const float b = bias[colg];
      if (bn < 2048) {
        u16* dst = (bn < 1024) ? Qh : Kh;
        const float sc = (bn < 1024) ? 0.18033688f : 1.0f;  // 0.125/ln2 (exp2 trick)
        const int hh = (colg & 1023) >> 6;
        const int dd = colg & 63;
#pragma unroll
        for (int r = 0; r < 4; ++r)
          dst[((size_t)hh * SEQ + row0 + r) * HD + dd] = f2bf((acc[m][n][r] + b) * sc);
      } else {
        const int dv = colg - 2048;
        const int hh = dv >> 6, dd = dv & 63;
        const int k5 = row0 & 31;            // 4-aligned key offset within 32-tile
        const int pos = (k5 < 16) ? ((k5 >> 2) * 8) : (((k5 - 16) >> 2) * 8 + 4);
        u16x4 pk;
#pragma unroll
        for (int r = 0; r < 4; ++r) pk[r] = f2bf(acc[m][n][r] + b);
        u16* vt = Vtile + ((((size_t)hh * NT32 + (row0 >> 5)) * HD + dd) << 5) + pos;
        *reinterpret_cast<u16x4*>(vt) = pk;
      }
    }
}

// Banded flash attention: block = 8 waves x 16 q-rows; union key range staged
// tile-by-tile (K 4KB + V 4KB) into 4-deep LDS ring via global_load_lds with
// counted vmcnt(2) (3 tiles in flight). Swapped QK^T (P lane-local, zero
// shuffles); XOR-swizzled LDS via pre-swizzled source + swizzled ds_read.
__global__ __launch_bounds__(512) void lf_attn(const u16* __restrict__ Qh, const u16* __restrict__ Kh,
                                               const u16* __restrict__ Vtile, const float* __restrict__ fm,
                                               float* __restrict__ out) {
  const int nwgx = gridDim.x;                       // 32
  const int nwg = nwgx * gridDim.y;                 // 512
  const int orig = blockIdx.y * nwgx + blockIdx.x;
  const int cpx = nwg >> 3;                         // 64
  const int wgid = (orig & 7) * cpx + (orig >> 3);  // bijective (512%8==0)
  const int h = wgid / nwgx;
  const int q0 = (wgid % nwgx) * BQ;
  const int tid = threadIdx.x;
  const int wid = tid >> 6, lane = tid & 63;
  const int lrow = lane & 15, lgrp = lane >> 4;
  const int qw = q0 + wid * 16;                     // this wave's 16 q-rows

  __shared__ __align__(16) u16 KL[4][32 * HD];      // 4 x 4KB
  __shared__ __align__(16) u16 VL[4][HD * 32];      // 4 x 4KB (sigma-permuted keys)

  bf16x8 qf0, qf1;
  {
    const u16* qbase = Qh + ((size_t)h * SEQ + qw + lrow) * HD + lgrp * 8;
    qf0 = *reinterpret_cast<const bf16x8*>(qbase);
    qf1 = *reinterpret_cast<const bf16x8*>(qbase + 32);
  }
  const f32x4 zero = {0.f, 0.f, 0.f, 0.f};
  f32x4 o_acc[4];
  float psum = 0.f;
#pragma unroll
  for (int g = 0; g < 4; ++g) o_acc[g] = zero;

  // Block-level union key range (all waves iterate it together).
  int kstart = q0 - WIN; if (kstart < 0) kstart = 0; kstart &= ~31;
  int kend = q0 + BQ - 1 + WIN + 1; if (kend > SEQ) kend = SEQ;   // multiple of 32
  const int NTT = (kend - kstart) >> 5;                           // >= 12

  const int q_abs = qw + lrow;  // this lane's q row (swapped layout)

  auto stage = [&](int t, int buf) {
    const int kt = kstart + t * 32;
    if (tid < 256) {
      const int row = tid >> 3, slot = tid & 7;     // K: 32 rows x 8 slots of 16B
      const u16* src = Kh + ((size_t)h * SEQ + kt + row) * HD + ((slot ^ (row & 7)) * 8);
      gload_lds16(src, &KL[buf][tid * 8]);
    } else {
      const int c = tid - 256;
      const int row = c >> 2, slot = c & 3;         // V: 64 rows x 4 slots of 16B
      const u16* src = Vtile + ((size_t)h * NT32 + (kt >> 5)) * (HD * 32) + row * 32 + ((slot ^ (row & 3)) * 8);
      gload_lds16(src, &VL[buf][c * 8]);
    }
  };

  stage(0, 0);
  stage(1, 1);
  stage(2, 2);
  asm volatile("s_waitcnt vmcnt(2)" ::: "memory");   // tile0 landed (1,2 may fly)
  asm volatile("s_barrier" ::: "memory");

  for (int t = 0; t < NTT; ++t) {
    const int s = t & 3;
    if (t + 3 < NTT) stage(t + 3, (t + 3) & 3);
    const int kt = kstart + t * 32;
    const bool active = (kt + 31 >= qw - WIN) && (kt <= qw + 15 + WIN);
    if (active) {
      const int xk = (lrow & 7) * 8;   // K swizzle (element units)
      const int xv = (lrow & 3) * 8;   // V swizzle
      const u16* KB = &KL[s][0];
      const u16* VB = &VL[s][0];
      const bf16x8 kf0 = *reinterpret_cast<const bf16x8*>(KB + lrow * 64        + (((lgrp)     * 8) ^ xk));
      const bf16x8 kf1 = *reinterpret_cast<const bf16x8*>(KB + lrow * 64        + (((lgrp + 4) * 8) ^ xk));
      const bf16x8 kf2 = *reinterpret_cast<const bf16x8*>(KB + (16 + lrow) * 64 + (((lgrp)     * 8) ^ xk));
      const bf16x8 kf3 = *reinterpret_cast<const bf16x8*>(KB + (16 + lrow) * 64 + (((lgrp + 4) * 8) ^ xk));
      const bf16x8 vf0 = *reinterpret_cast<const bf16x8*>(VB + lrow * 32        + ((lgrp * 8) ^ xv));
      const bf16x8 vf1 = *reinterpret_cast<const bf16x8*>(VB + (16 + lrow) * 32 + ((lgrp * 8) ^ xv));
      const bf16x8 vf2 = *reinterpret_cast<const bf16x8*>(VB + (32 + lrow) * 32 + ((lgrp * 8) ^ xv));
      const bf16x8 vf3 = *reinterpret_cast<const bf16x8*>(VB + (48 + lrow) * 32 + ((lgrp * 8) ^ xv));

      f32x4 s0 = zero, s1 = zero;
      s0 = __builtin_amdgcn_mfma_f32_16x16x32_bf16(kf0, qf0, s0, 0, 0, 0);
      s0 = __builtin_amdgcn_mfma_f32_16x16x32_bf16(kf1, qf1, s0, 0, 0, 0);
      s1 = __builtin_amdgcn_mfma_f32_16x16x32_bf16(kf2, qf0, s1, 0, 0, 0);
      s1 = __builtin_amdgcn_mfma_f32_16x16x32_bf16(kf3, qf1, s1, 0, 0, 0);

      const float4 f0 = *reinterpret_cast<const float4*>(fm + kt + lgrp * 4);
      const float4 f1 = *reinterpret_cast<const float4*>(fm + kt + 16 + lgrp * 4);
      const float f0v[4] = {f0.x, f0.y, f0.z, f0.w};
      const float f1v[4] = {f1.x, f1.y, f1.z, f1.w};

      u16x8 pu;
      if (kt >= qw - 241 && kt <= qw + 225) {
#pragma unroll
        for (int r = 0; r < 4; ++r) {
          const float e0 = __builtin_amdgcn_exp2f(s0[r] + f0v[r]);
          const float e1 = __builtin_amdgcn_exp2f(s1[r] + f1v[r]);
          psum += e0 + e1;
          pu[r] = f2bf(e0);
          pu[4 + r] = f2bf(e1);
        }
      } else {
#pragma unroll
        for (int r = 0; r < 4; ++r) {
          const int key0 = kt + lgrp * 4 + r;
          const int d0 = key0 - q_abs + WIN;   // valid iff 0 <= d0 <= 2*WIN
          const float e0 = ((unsigned)d0 <= 2u * WIN) ? __builtin_amdgcn_exp2f(s0[r] + f0v[r]) : 0.f;
          const float e1 = ((unsigned)(d0 + 16) <= 2u * WIN) ? __builtin_amdgcn_exp2f(s1[r] + f1v[r]) : 0.f;
          psum += e0 + e1;
          pu[r] = f2bf(e0);
          pu[4 + r] = f2bf(e1);
        }
      }
      const bf16x8 pa = __builtin_bit_cast(bf16x8, pu);
      o_acc[0] = __builtin_amdgcn_mfma_f32_16x16x32_bf16(pa, vf0, o_acc[0], 0, 0, 0);
      o_acc[1] = __builtin_amdgcn_mfma_f32_16x16x32_bf16(pa, vf1, o_acc[1], 0, 0, 0);
      o_acc[2] = __builtin_amdgcn_mfma_f32_16x16x32_bf16(pa, vf2, o_acc[2], 0, 0, 0);
      o_acc[3] = __builtin_amdgcn_mfma_f32_16x16x32_bf16(pa, vf3, o_acc[3], 0, 0, 0);
    }
    if (t + 3 < NTT)      { asm volatile("s_waitcnt vmcnt(2)" ::: "memory"); }
    else if (t + 2 < NTT) { asm volatile("s_waitcnt vmcnt(1)" ::: "memory"); }
    else if (t + 1 < NTT) { asm volatile("s_waitcnt vmcnt(0)" ::: "memory"); }
    asm volatile("s_barrier" ::: "memory");
  }

  psum += __shfl_xor(psum, 16);
  psum += __shfl_xor(psum, 32);

  float psr[4];
#pragma unroll
  for (int r = 0; r < 4; ++r) psr[r] = __shfl(psum, lgrp * 4 + r, 64);
#pragma unroll
  for (int g = 0; g < 4; ++g)
#pragma unroll
    for (int r = 0; r < 4; ++r) {
      const int row = qw + lgrp * 4 + r;
      out[(size_t)row * DIM + h * HD + g * 16 + lrow] = o_acc[g][r] / psr[r];
    }
}

extern "C" void kernel_launch(void* const* d_in, const int* in_sizes, int n_in,
                              void* d_out, int out_size, void* d_ws, size_t ws_size,
                              hipStream_t stream) {
  const float* hsrc  = (const float*)d_in[0];
  const float* amask = (const float*)d_in[1];
  const float* Wq = (const float*)d_in[3];
  const float* bq = (const float*)d_in[4];
  const float* Wk = (const float*)d_in[5];
  const float* bk = (const float*)d_in[6];
  const float* Wv = (const float*)d_in[7];
  const float* bv = (const float*)d_in[8];
  float* out = (float*)d_out;
  char* ws = (char*)d_ws;
  const size_t MB = 1024 * 1024;
  u16*   Hb      = (u16*)(ws);                 // 8 MB: hidden bf16 [4096][1024]
  u16*   Wcat    = (u16*)(ws + 8 * MB);        // 6 MB: [3072][1024] bf16 (Wq|Wk|Wv)
  float* auxbuf  = (float*)(ws + 14 * MB);     // 28 KB: bias[3072] | fm[4096]
  u16*   Qh      = (u16*)(ws + 15 * MB);       // 8 MB: [NH][S][64] (pre-scaled by 0.125/ln2)
  u16*   Kh      = (u16*)(ws + 23 * MB);       // 8 MB: [NH][S][64]
  u16*   Vtile   = (u16*)(ws + 31 * MB);       // 8 MB: [NH][S/32][64][32] sigma-permuted

  cast_all<<<7196, 256, 0, stream>>>(hsrc, Wq, Wk, Wv, bq, bk, bv, amask, Hb, Wcat, auxbuf);

  dim3 gq(3 * DIM / 128, SEQ / 128);  // (24, 32) = 768 blocks
  gemm_qkv<<<gq, 256, 0, stream>>>(Hb, Wcat, auxbuf, Qh, Kh, Vtile);

  dim3 ga(SEQ / BQ, NH);              // (32, 16) -> 512 blocks x 8 waves
  lf_attn<<<ga, 512, 0, stream>>>(Qh, Kh, Vtile, auxbuf + 3072, out);
}

// Round 16
// 68.765 us; speedup vs baseline: 1.0643x; 1.0643x over previous
//
#include <hip/hip_runtime.h>
#include <hip/hip_bf16.h>

typedef unsigned short u16;
typedef __attribute__((ext_vector_type(8))) __bf16 bf16x8;
typedef __attribute__((ext_vector_type(8))) unsigned short u16x8;
typedef __attribute__((ext_vector_type(4))) float f32x4;
typedef __attribute__((ext_vector_type(4))) unsigned short u16x4;

#define SEQ 4096
#define DIM 1024
#define NH 16
#define HD 64
#define WIN 256
#define NT32 (SEQ / 32)
#define NKT 32   // K-tiles of 32 in K=1024 (projection GEMM)
#define BQ 128   // q-rows per attention block

__device__ inline u16 f2bf(float f) {
  __hip_bfloat16 h = __float2bfloat16(f);
  return __builtin_bit_cast(u16, h);
}

__device__ inline void gload_lds16(const void* g, void* l) {
  auto gp = reinterpret_cast<__attribute__((address_space(1))) unsigned int*>(
      reinterpret_cast<unsigned long long>(g));
  auto lp = reinterpret_cast<__attribute__((address_space(3))) unsigned int*>(
      reinterpret_cast<unsigned long long>(l));
  __builtin_amdgcn_global_load_lds(gp, lp, 16, 0, 0);
}

// Fused cast (hidden + 3 weights -> bf16) + aux pack (bias cat + fm mask table).
__global__ __launch_bounds__(256) void cast_all(const float* __restrict__ hsrc,
                                                const float* __restrict__ w0, const float* __restrict__ w1,
                                                const float* __restrict__ w2,
                                                const float* __restrict__ b0, const float* __restrict__ b1,
                                                const float* __restrict__ b2, const float* __restrict__ amask,
                                                u16* __restrict__ Hb, u16* __restrict__ Wcat,
                                                float* __restrict__ aux) {
  const int bid = blockIdx.x;
  if (bid < 7168) {
    int i = (bid * 256 + threadIdx.x) * 4;
    const float* src;
    u16* dst;
    if (i < (1 << 22)) { src = hsrc + i; dst = Hb + i; }
    else {
      int j = i - (1 << 22);
      const int seg = j >> 20, loc = j & ((1 << 20) - 1);
      src = ((seg == 0) ? w0 : (seg == 1) ? w1 : w2) + loc;
      dst = Wcat + j;
    }
    const float4 v = *reinterpret_cast<const float4*>(src);
    u16x4 r;
    r.x = f2bf(v.x); r.y = f2bf(v.y); r.z = f2bf(v.z); r.w = f2bf(v.w);
    *reinterpret_cast<u16x4*>(dst) = r;
  } else {
    int i = (bid - 7168) * 256 + threadIdx.x;   // 0..7167
    if (i < 3072) {
      const int seg = i >> 10, loc = i & 1023;
      aux[i] = (seg == 0) ? b0[loc] : (seg == 1) ? b1[loc] : b2[loc];
    } else {
      const int j = i - 3072;
      aux[i] = (amask[j] != 0.f) ? -14426.95f : 0.f;   // -10000/ln2
    }
  }
}

// ---- GEMM (r13-proven): 256(M)x128(N) tile, BK=32, 4 waves (2Mx2N), per-wave
// 128x64 (8x4 acc; 12 ds_read_b128 per 32 MFMA). Tri-buffered counted-vmcnt
// pipeline; both-sides XOR-swizzled LDS (linear dest, pre-swizzled source,
// swizzled read): 16B unit u = sr*8 + half*4 + sp holds global (row = sr*2+half,
// slot = sp ^ (sr&3)); read elem = (row>>1)*64 + (row&1)*32 + (lgrp^((row>>1)&3))*8.
__device__ __forceinline__ void stage_tile(const u16* __restrict__ A, const u16* __restrict__ B,
                                           int bm, int bn, u16* sa, u16* sb, int kt, int tid) {
  const int k0 = kt * 32;
#pragma unroll
  for (int l = 0; l < 4; ++l) {                // A: 256x32 = 1024 units of 16B
    const int u = l * 256 + tid;
    const int sr = u >> 3, half = (u >> 2) & 1, sp = u & 3;
    const int row = sr * 2 + half;
    const int slot = sp ^ (sr & 3);
    gload_lds16(A + (size_t)(bm + row) * DIM + k0 + slot * 8, sa + u * 8);
  }
#pragma unroll
  for (int l = 0; l < 2; ++l) {                // B: 128x32 = 512 units of 16B
    const int u = l * 256 + tid;
    const int sr = u >> 3, half = (u >> 2) & 1, sp = u & 3;
    const int row = sr * 2 + half;
    const int slot = sp ^ (sr & 3);
    gload_lds16(B + (size_t)(bn + row) * DIM + k0 + slot * 8, sb + u * 8);
  }
}

// Fused QKV projection.
// Cols 0-1023    -> Qh [NH][S][64]  (x 0.125/ln2, exp2 trick)
// Cols 1024-2047 -> Kh [NH][S][64]
// Cols 2048-3071 -> Vtile [NH][S/32][64][32], sigma-permuted keys (zero-shuffle PV).
__global__ __launch_bounds__(256, 2) void gemm_qkv(const u16* __restrict__ A, const u16* __restrict__ B,
                                                   const float* __restrict__ bias,
                                                   u16* __restrict__ Qh, u16* __restrict__ Kh,
                                                   u16* __restrict__ Vtile) {
  __shared__ __align__(16) u16 SA[3][256 * 32];
  __shared__ __align__(16) u16 SB[3][128 * 32];
  const int nwgx = gridDim.x;                        // 24
  const int orig = blockIdx.y * nwgx + blockIdx.x;   // 0..383
  const int cpx = (nwgx * gridDim.y) >> 3;           // 48
  const int wgid = (orig & 7) * cpx + (orig >> 3);   // bijective (384%8==0)
  const int bm = (wgid / nwgx) * 256, bn = (wgid % nwgx) * 128;
  const int tid = threadIdx.x;
  const int lane = tid & 63, wid = tid >> 6;
  const int lrow = lane & 15, lgrp = lane >> 4;
  const int wr = (wid >> 1) * 128, wc = (wid & 1) * 64;

  f32x4 acc[8][4];
  const f32x4 zero = {0.f, 0.f, 0.f, 0.f};
#pragma unroll
  for (int m = 0; m < 8; ++m)
#pragma unroll
    for (int n = 0; n < 4; ++n) acc[m][n] = zero;

  stage_tile(A, B, bm, bn, SA[0], SB[0], 0, tid);
  stage_tile(A, B, bm, bn, SA[1], SB[1], 1, tid);
  asm volatile("s_waitcnt vmcnt(6)" ::: "memory");   // tile0 landed (tile1 may fly)
  asm volatile("s_barrier" ::: "memory");

  for (int t = 0; t < NKT; ++t) {
    const int s = t % 3;
    if (t + 2 < NKT) stage_tile(A, B, bm, bn, SA[(t + 2) % 3], SB[(t + 2) % 3], t + 2, tid);
    bf16x8 af[8], bfr[4];
#pragma unroll
    for (int m = 0; m < 8; ++m) {
      const int row = wr + m * 16 + lrow;
      af[m] = *reinterpret_cast<const bf16x8*>(
          &SA[s][(row >> 1) * 64 + (row & 1) * 32 + ((lgrp ^ ((row >> 1) & 3)) * 8)]);
    }
#pragma unroll
    for (int n = 0; n < 4; ++n) {
      const int row = wc + n * 16 + lrow;
      bfr[n] = *reinterpret_cast<const bf16x8*>(
          &SB[s][(row >> 1) * 64 + (row & 1) * 32 + ((lgrp ^ ((row >> 1) & 3)) * 8)]);
    }
    __builtin_amdgcn_s_setprio(1);
#pragma unroll
    for (int m = 0; m < 8; ++m)
#pragma unroll
      for (int n = 0; n < 4; ++n)
        acc[m][n] = __builtin_amdgcn_mfma_f32_16x16x32_bf16(af[m], bfr[n], acc[m][n], 0, 0, 0);
    __builtin_amdgcn_s_setprio(0);
    if (t + 2 < NKT) { asm volatile("s_waitcnt vmcnt(6)" ::: "memory"); }
    else if (t + 1 < NKT) { asm volatile("s_waitcnt vmcnt(0)" ::: "memory"); }
    asm volatile("s_barrier" ::: "memory");
  }

#pragma unroll
  for (int m = 0; m < 8; ++m)
#pragma unroll
    for (int n = 0; n < 4; ++n) {
      const int row0 = bm + wr + m * 16 + lgrp * 4;
      const int colg = bn + wc + n * 16 + lrow;
      const float b = bias[colg];
      if (bn < 2048) {
        u16* dst = (bn < 1024) ? Qh : Kh;
        const float sc = (bn < 1024) ? 0.18033688f : 1.0f;  // 0.125/ln2 (exp2 trick)
        const int hh = (colg & 1023) >> 6;
        const int dd = colg & 63;
#pragma unroll
        for (int r = 0; r < 4; ++r)
          dst[((size_t)hh * SEQ + row0 + r) * HD + dd] = f2bf((acc[m][n][r] + b) * sc);
      } else {
        const int dv = colg - 2048;
        const int hh = dv >> 6, dd = dv & 63;
        const int k5 = row0 & 31;            // 4-aligned key offset within 32-tile
        const int pos = (k5 < 16) ? ((k5 >> 2) * 8) : (((k5 - 16) >> 2) * 8 + 4);
        u16x4 pk;
#pragma unroll
        for (int r = 0; r < 4; ++r) pk[r] = f2bf(acc[m][n][r] + b);
        u16* vt = Vtile + ((((size_t)hh * NT32 + (row0 >> 5)) * HD + dd) << 5) + pos;
        *reinterpret_cast<u16x4*>(vt) = pk;
      }
    }
}

// Banded flash attention (r15 config): block = 8 waves x 16 q-rows; union key
// range staged tile-by-tile (K 4KB + V 4KB) into 4-deep LDS ring via
// global_load_lds with counted vmcnt(2) (3 tiles in flight). Swapped QK^T
// (P lane-local, zero shuffles); XOR-swizzled LDS via pre-swizzled source +
// swizzled ds_read.
__global__ __launch_bounds__(512) void lf_attn(const u16* __restrict__ Qh, const u16* __restrict__ Kh,
                                               const u16* __restrict__ Vtile, const float* __restrict__ fm,
                                               float* __restrict__ out) {
  const int nwgx = gridDim.x;                       // 32
  const int nwg = nwgx * gridDim.y;                 // 512
  const int orig = blockIdx.y * nwgx + blockIdx.x;
  const int cpx = nwg >> 3;                         // 64
  const int wgid = (orig & 7) * cpx + (orig >> 3);  // bijective (512%8==0)
  const int h = wgid / nwgx;
  const int q0 = (wgid % nwgx) * BQ;
  const int tid = threadIdx.x;
  const int wid = tid >> 6, lane = tid & 63;
  const int lrow = lane & 15, lgrp = lane >> 4;
  const int qw = q0 + wid * 16;                     // this wave's 16 q-rows

  __shared__ __align__(16) u16 KL[4][32 * HD];      // 4 x 4KB
  __shared__ __align__(16) u16 VL[4][HD * 32];      // 4 x 4KB (sigma-permuted keys)

  bf16x8 qf0, qf1;
  {
    const u16* qbase = Qh + ((size_t)h * SEQ + qw + lrow) * HD + lgrp * 8;
    qf0 = *reinterpret_cast<const bf16x8*>(qbase);
    qf1 = *reinterpret_cast<const bf16x8*>(qbase + 32);
  }
  const f32x4 zero = {0.f, 0.f, 0.f, 0.f};
  f32x4 o_acc[4];
  float psum = 0.f;
#pragma unroll
  for (int g = 0; g < 4; ++g) o_acc[g] = zero;

  // Block-level union key range (all waves iterate it together).
  int kstart = q0 - WIN; if (kstart < 0) kstart = 0; kstart &= ~31;
  int kend = q0 + BQ - 1 + WIN + 1; if (kend > SEQ) kend = SEQ;   // multiple of 32
  const int NTT = (kend - kstart) >> 5;                           // >= 12

  const int q_abs = qw + lrow;  // this lane's q row (swapped layout)

  auto stage = [&](int t, int buf) {
    const int kt = kstart + t * 32;
    if (tid < 256) {
      const int row = tid >> 3, slot = tid & 7;     // K: 32 rows x 8 slots of 16B
      const u16* src = Kh + ((size_t)h * SEQ + kt + row) * HD + ((slot ^ (row & 7)) * 8);
      gload_lds16(src, &KL[buf][tid * 8]);
    } else {
      const int c = tid - 256;
      const int row = c >> 2, slot = c & 3;         // V: 64 rows x 4 slots of 16B
      const u16* src = Vtile + ((size_t)h * NT32 + (kt >> 5)) * (HD * 32) + row * 32 + ((slot ^ (row & 3)) * 8);
      gload_lds16(src, &VL[buf][c * 8]);
    }
  };

  stage(0, 0);
  stage(1, 1);
  stage(2, 2);
  asm volatile("s_waitcnt vmcnt(2)" ::: "memory");   // tile0 landed (1,2 may fly)
  asm volatile("s_barrier" ::: "memory");

  for (int t = 0; t < NTT; ++t) {
    const int s = t & 3;
    if (t + 3 < NTT) stage(t + 3, (t + 3) & 3);
    const int kt = kstart + t * 32;
    const bool active = (kt + 31 >= qw - WIN) && (kt <= qw + 15 + WIN);
    if (active) {
      const int xk = (lrow & 7) * 8;   // K swizzle (element units)
      const int xv = (lrow & 3) * 8;   // V swizzle
      const u16* KB = &KL[s][0];
      const u16* VB = &VL[s][0];
      const bf16x8 kf0 = *reinterpret_cast<const bf16x8*>(KB + lrow * 64        + (((lgrp)     * 8) ^ xk));
      const bf16x8 kf1 = *reinterpret_cast<const bf16x8*>(KB + lrow * 64        + (((lgrp + 4) * 8) ^ xk));
      const bf16x8 kf2 = *reinterpret_cast<const bf16x8*>(KB + (16 + lrow) * 64 + (((lgrp)     * 8) ^ xk));
      const bf16x8 kf3 = *reinterpret_cast<const bf16x8*>(KB + (16 + lrow) * 64 + (((lgrp + 4) * 8) ^ xk));
      const bf16x8 vf0 = *reinterpret_cast<const bf16x8*>(VB + lrow * 32        + ((lgrp * 8) ^ xv));
      const bf16x8 vf1 = *reinterpret_cast<const bf16x8*>(VB + (16 + lrow) * 32 + ((lgrp * 8) ^ xv));
      const bf16x8 vf2 = *reinterpret_cast<const bf16x8*>(VB + (32 + lrow) * 32 + ((lgrp * 8) ^ xv));
      const bf16x8 vf3 = *reinterpret_cast<const bf16x8*>(VB + (48 + lrow) * 32 + ((lgrp * 8) ^ xv));

      f32x4 s0 = zero, s1 = zero;
      s0 = __builtin_amdgcn_mfma_f32_16x16x32_bf16(kf0, qf0, s0, 0, 0, 0);
      s0 = __builtin_amdgcn_mfma_f32_16x16x32_bf16(kf1, qf1, s0, 0, 0, 0);
      s1 = __builtin_amdgcn_mfma_f32_16x16x32_bf16(kf2, qf0, s1, 0, 0, 0);
      s1 = __builtin_amdgcn_mfma_f32_16x16x32_bf16(kf3, qf1, s1, 0, 0, 0);

      const float4 f0 = *reinterpret_cast<const float4*>(fm + kt + lgrp * 4);
      const float4 f1 = *reinterpret_cast<const float4*>(fm + kt + 16 + lgrp * 4);
      const float f0v[4] = {f0.x, f0.y, f0.z, f0.w};
      const float f1v[4] = {f1.x, f1.y, f1.z, f1.w};

      u16x8 pu;
      if (kt >= qw - 241 && kt <= qw + 225) {
#pragma unroll
        for (int r = 0; r < 4; ++r) {
          const float e0 = __builtin_amdgcn_exp2f(s0[r] + f0v[r]);
          const float e1 = __builtin_amdgcn_exp2f(s1[r] + f1v[r]);
          psum += e0 + e1;
          pu[r] = f2bf(e0);
          pu[4 + r] = f2bf(e1);
        }
      } else {
#pragma unroll
        for (int r = 0; r < 4; ++r) {
          const int key0 = kt + lgrp * 4 + r;
          const int d0 = key0 - q_abs + WIN;   // valid iff 0 <= d0 <= 2*WIN
          const float e0 = ((unsigned)d0 <= 2u * WIN) ? __builtin_amdgcn_exp2f(s0[r] + f0v[r]) : 0.f;
          const float e1 = ((unsigned)(d0 + 16) <= 2u * WIN) ? __builtin_amdgcn_exp2f(s1[r] + f1v[r]) : 0.f;
          psum += e0 + e1;
          pu[r] = f2bf(e0);
          pu[4 + r] = f2bf(e1);
        }
      }
      const bf16x8 pa = __builtin_bit_cast(bf16x8, pu);
      o_acc[0] = __builtin_amdgcn_mfma_f32_16x16x32_bf16(pa, vf0, o_acc[0], 0, 0, 0);
      o_acc[1] = __builtin_amdgcn_mfma_f32_16x16x32_bf16(pa, vf1, o_acc[1], 0, 0, 0);
      o_acc[2] = __builtin_amdgcn_mfma_f32_16x16x32_bf16(pa, vf2, o_acc[2], 0, 0, 0);
      o_acc[3] = __builtin_amdgcn_mfma_f32_16x16x32_bf16(pa, vf3, o_acc[3], 0, 0, 0);
    }
    if (t + 3 < NTT)      { asm volatile("s_waitcnt vmcnt(2)" ::: "memory"); }
    else if (t + 2 < NTT) { asm volatile("s_waitcnt vmcnt(1)" ::: "memory"); }
    else if (t + 1 < NTT) { asm volatile("s_waitcnt vmcnt(0)" ::: "memory"); }
    asm volatile("s_barrier" ::: "memory");
  }

  psum += __shfl_xor(psum, 16);
  psum += __shfl_xor(psum, 32);

  float psr[4];
#pragma unroll
  for (int r = 0; r < 4; ++r) psr[r] = __shfl(psum, lgrp * 4 + r, 64);
#pragma unroll
  for (int g = 0; g < 4; ++g)
#pragma unroll
    for (int r = 0; r < 4; ++r) {
      const int row = qw + lgrp * 4 + r;
      out[(size_t)row * DIM + h * HD + g * 16 + lrow] = o_acc[g][r] / psr[r];
    }
}

extern "C" void kernel_launch(void* const* d_in, const int* in_sizes, int n_in,
                              void* d_out, int out_size, void* d_ws, size_t ws_size,
                              hipStream_t stream) {
  const float* hsrc  = (const float*)d_in[0];
  const float* amask = (const float*)d_in[1];
  const float* Wq = (const float*)d_in[3];
  const float* bq = (const float*)d_in[4];
  const float* Wk = (const float*)d_in[5];
  const float* bk = (const float*)d_in[6];
  const float* Wv = (const float*)d_in[7];
  const float* bv = (const float*)d_in[8];
  float* out = (float*)d_out;
  char* ws = (char*)d_ws;
  const size_t MB = 1024 * 1024;
  u16*   Hb      = (u16*)(ws);                 // 8 MB: hidden bf16 [4096][1024]
  u16*   Wcat    = (u16*)(ws + 8 * MB);        // 6 MB: [3072][1024] bf16 (Wq|Wk|Wv)
  float* auxbuf  = (float*)(ws + 14 * MB);     // 28 KB: bias[3072] | fm[4096]
  u16*   Qh      = (u16*)(ws + 15 * MB);       // 8 MB: [NH][S][64] (pre-scaled by 0.125/ln2)
  u16*   Kh      = (u16*)(ws + 23 * MB);       // 8 MB: [NH][S][64]
  u16*   Vtile   = (u16*)(ws + 31 * MB);       // 8 MB: [NH][S/32][64][32] sigma-permuted

  cast_all<<<7196, 256, 0, stream>>>(hsrc, Wq, Wk, Wv, bq, bk, bv, amask, Hb, Wcat, auxbuf);

  dim3 gq(3 * DIM / 128, SEQ / 256);  // (24, 16) = 384 blocks
  gemm_qkv<<<gq, 256, 0, stream>>>(Hb, Wcat, auxbuf, Qh, Kh, Vtile);

  dim3 ga(SEQ / BQ, NH);              // (32, 16) -> 512 blocks x 8 waves
  lf_attn<<<ga, 512, 0, stream>>>(Qh, Kh, Vtile, auxbuf + 3072, out);
}